// Round 6
// baseline (550.282 us; speedup 1.0000x reference)
//
#include <hip/hip_runtime.h>
#include <math.h>

// EdgeConvGNN: 2-layer GCN on a line graph; output = sigmoid(h2[idx0].Wl+bl).
// Only the 2-hop neighborhood of idx0 is live (E[deg]=10 -> ~120 nodes).
// Measured: each stream-ordered stage boundary costs ~15-20us (launch + L2
// flush), 5 stages ~= 90us of pure overhead. So: ONE cooperative kernel with
// lightweight one-fence-per-block barriers (R2's 100us/phase was a per-thread
// fence storm + cg::sync, not inherent cost). Phases:
//   A scan col[] -> list1 (col==idx0), S2 = {idx0} U rows   (bit dedup)
//   B scan col[] -> list2 (col in S2), S3 = S2 U rows(list2)
//   C blocks<960: degc[slot[c]]++ for c in S3 (~1.2K memory-side atomics)
//     blocks>=960: hw0[b] = concat(x[src],x[dst]) @ W0 per S3 node
//   D block b<ns2: LDS-stage list2; h1=relu(agg+self+b0); hw1=h1@W1
//   E block 0: final aggregate at idx0 (parallel over rows) + sigmoid
// Cross-phase visibility: control state via memory-side device atomics;
// bulk data (lists, hw0, hw1) is flushed by the writer's tid0 release-fence
// (buffer_wbl2) and first-touched by readers only after the barrier.

#define MAX_L1 512
#define MAX_S2 (MAX_L1 + 8)
#define MAX_L2 4096
#define MAX_S3 (MAX_L2 + MAX_S2 + 8)
#define GRID_B 1024
#define HW0_B 64
#define SCAN_C (GRID_B - HW0_B)
#define LDSE 1024

enum { CNT_L1 = 0, CNT_S2 = 1, CNT_L2 = 2, CNT_S3 = 3,
       BAR_A = 8, BAR_B = 9, BAR_C = 10, BAR_D = 11 };

// light grid barrier: one release-fence + one acquire-fence per BLOCK.
__device__ __forceinline__ void gbar(int* ctr, int expected) {
  __syncthreads();  // all block waves' stores drained (write-through to L2)
  if (threadIdx.x == 0) {
    __threadfence();            // release: wbl2 this XCD's L2
    atomicAdd(ctr, 1);          // memory-side, device-coherent
    while (__hip_atomic_load(ctr, __ATOMIC_RELAXED,
                             __HIP_MEMORY_SCOPE_AGENT) < expected)
      __builtin_amdgcn_s_sleep(4);
    __threadfence();            // acquire: invalidate stale L1/L2 lines
  }
  __syncthreads();
}

__device__ __forceinline__ void insert_s3(int n, unsigned* bits3, int* cnt,
                                          int* s3_list, int* slot) {
  unsigned m = 1u << (n & 31);
  if (!(atomicOr(&bits3[n >> 5], m) & m)) {
    int p = atomicAdd(&cnt[CNT_S3], 1);
    if (p < MAX_S3) { s3_list[p] = n; slot[n] = p; }
  }
}

__device__ __forceinline__ void insert_s2(int n, unsigned* bits2, int* cnt,
                                          int* s2_list, int* s2pos,
                                          unsigned* bits3, int* s3_list,
                                          int* slot) {
  unsigned m = 1u << (n & 31);
  if (!(atomicOr(&bits2[n >> 5], m) & m)) {
    int p = atomicAdd(&cnt[CNT_S2], 1);
    if (p < MAX_S2) { s2_list[p] = n; s2pos[n] = p; }
  }
  insert_s3(n, bits3, cnt, s3_list, slot);
}

__global__ void __launch_bounds__(256)
fused_gnn(const float* __restrict__ x, const int* __restrict__ g,
          const int* __restrict__ lg, const int* __restrict__ pidx,
          const float* __restrict__ W0, const float* __restrict__ b0,
          const float* __restrict__ W1, const float* __restrict__ b1,
          const float* __restrict__ Wl, const float* __restrict__ bl,
          float* __restrict__ out,
          int* __restrict__ cnt, unsigned* __restrict__ bits2,
          unsigned* __restrict__ bits3, int* __restrict__ degc,
          int* __restrict__ list1, int* __restrict__ s2_list,
          int* __restrict__ s2pos, int2* __restrict__ list2,
          int* __restrict__ s3_list, int* __restrict__ slot,
          float* __restrict__ hw0, float* __restrict__ hw1,
          int e_g, int e_lg) {
  const int tid = threadIdx.x;
  const int gtid = blockIdx.x * blockDim.x + tid;
  const int gstride = GRID_B * 256;
  const int idx0 = pidx[0];
  const int* __restrict__ col = lg + e_lg;
  const int n4 = ((((uintptr_t)col) & 15) == 0) ? (e_lg >> 2) : 0;
  const int4* __restrict__ col4 = (const int4*)col;

  __shared__ int2 eLDS[LDSE];
  __shared__ float part[2][128];
  __shared__ float h1s[128];

  // ---- phase A: list1 = edges with col==idx0; S2 = {idx0} U rows ----
  if (gtid == 0)
    insert_s2(idx0, bits2, cnt, s2_list, s2pos, bits3, s3_list, slot);
  for (int i = gtid; i < n4; i += gstride) {
    int4 v = col4[i];
    int cc[4] = {v.x, v.y, v.z, v.w};
#pragma unroll
    for (int k = 0; k < 4; ++k) {
      if (cc[k] == idx0) {
        int r = lg[i * 4 + k];
        int p = atomicAdd(&cnt[CNT_L1], 1);
        if (p < MAX_L1) list1[p] = r;
        insert_s2(r, bits2, cnt, s2_list, s2pos, bits3, s3_list, slot);
      }
    }
  }
  for (int e = n4 * 4 + gtid; e < e_lg; e += gstride) {
    if (col[e] == idx0) {
      int r = lg[e];
      int p = atomicAdd(&cnt[CNT_L1], 1);
      if (p < MAX_L1) list1[p] = r;
      insert_s2(r, bits2, cnt, s2_list, s2pos, bits3, s3_list, slot);
    }
  }
  gbar(&cnt[BAR_A], GRID_B);

  // ---- phase B: list2 = edges with col in S2; S3 += rows(list2) ----
  for (int i = gtid; i < n4; i += gstride) {
    int4 v = col4[i];
    int cc[4] = {v.x, v.y, v.z, v.w};
#pragma unroll
    for (int k = 0; k < 4; ++k) {
      int c = cc[k];
      if ((bits2[c >> 5] >> (c & 31)) & 1u) {
        int r = lg[i * 4 + k];
        int p = atomicAdd(&cnt[CNT_L2], 1);
        if (p < MAX_L2) list2[p] = make_int2(r, c);
        insert_s3(r, bits3, cnt, s3_list, slot);
      }
    }
  }
  for (int e = n4 * 4 + gtid; e < e_lg; e += gstride) {
    int c = col[e];
    if ((bits2[c >> 5] >> (c & 31)) & 1u) {
      int r = lg[e];
      int p = atomicAdd(&cnt[CNT_L2], 1);
      if (p < MAX_L2) list2[p] = make_int2(r, c);
      insert_s3(r, bits3, cnt, s3_list, slot);
    }
  }
  gbar(&cnt[BAR_B], GRID_B);

  // ---- phase C: deg scan (blocks < SCAN_C) || hw0 matvecs (last 64) ----
  if (blockIdx.x < SCAN_C) {
    const int sgtid = blockIdx.x * 256 + tid;
    const int sstride = SCAN_C * 256;
    for (int i = sgtid; i < n4; i += sstride) {
      int4 v = col4[i];
      int cc[4] = {v.x, v.y, v.z, v.w};
#pragma unroll
      for (int k = 0; k < 4; ++k) {
        int c = cc[k];
        if ((bits3[c >> 5] >> (c & 31)) & 1u) atomicAdd(&degc[slot[c]], 1);
      }
    }
    for (int e = n4 * 4 + sgtid; e < e_lg; e += sstride) {
      int c = col[e];
      if ((bits3[c >> 5] >> (c & 31)) & 1u) atomicAdd(&degc[slot[c]], 1);
    }
  } else {
    int ns3 = min(cnt[CNT_S3], MAX_S3);
    int hb = (blockIdx.x - SCAN_C) * 2 + (tid >> 7);
    int t = tid & 127;
    for (int b = hb; b < ns3; b += HW0_B * 2) {
      int node = s3_list[b];
      int src = g[node];
      int dst = g[e_g + node];
      float acc = 0.f;
#pragma unroll 8
      for (int k = 0; k < 64; ++k) acc += x[src * 64 + k] * W0[k * 128 + t];
#pragma unroll 8
      for (int k = 0; k < 64; ++k) acc += x[dst * 64 + k] * W0[(64 + k) * 128 + t];
      hw0[b * 128 + t] = acc;
    }
  }
  gbar(&cnt[BAR_C], GRID_B);

  // ---- phase D: per S2 node, h1 = relu(agg+self+b0); hw1 = h1 @ W1 ----
  {
    int ns2 = min(cnt[CNT_S2], MAX_S2);
    int n2 = min(cnt[CNT_L2], MAX_L2);
    if ((int)blockIdx.x < ns2) {
      int t = tid & 127;
      int grp = tid >> 7;
      int j = s2_list[blockIdx.x];
      int n2l = min(n2, LDSE);
      for (int i = tid; i < n2l; i += 256) eLDS[i] = list2[i];
      __syncthreads();
      float dj = rsqrtf((float)degc[slot[j]] + 1.0f);
      float acc = (grp == 0) ? hw0[slot[j] * 128 + t] * dj * dj + b0[t] : 0.f;
      for (int i = grp; i < n2; i += 2) {
        int2 e = (i < LDSE) ? eLDS[i] : list2[i];
        if (e.y == j) {
          float dr = rsqrtf((float)degc[slot[e.x]] + 1.0f);
          acc += hw0[slot[e.x] * 128 + t] * (dr * dj);
        }
      }
      part[grp][t] = acc;
      __syncthreads();
      if (grp == 0) h1s[t] = fmaxf(part[0][t] + part[1][t], 0.f);
      __syncthreads();
      float a2 = 0.f;
      int k0 = grp * 64;
#pragma unroll 8
      for (int k = 0; k < 64; ++k) a2 += h1s[k0 + k] * W1[(k0 + k) * 128 + t];
      part[grp][t] = a2;
      __syncthreads();
      if (grp == 0) hw1[blockIdx.x * 128 + t] = part[0][t] + part[1][t];
    }
  }
  gbar(&cnt[BAR_D], GRID_B);

  // ---- phase E: final aggregate at idx0 + sigmoid (block 0) ----
  if (blockIdx.x == 0) {
    int t = tid & 127;
    int grp = tid >> 7;
    float d0 = rsqrtf((float)degc[slot[idx0]] + 1.0f);
    float facc = (grp == 0) ? hw1[s2pos[idx0] * 128 + t] * d0 * d0 : 0.f;
    int n1 = min(cnt[CNT_L1], MAX_L1);
    for (int i = grp; i < n1; i += 2) {
      int r = list1[i];
      float dr = rsqrtf((float)degc[slot[r]] + 1.0f);
      facc += hw1[s2pos[r] * 128 + t] * (dr * d0);
    }
    part[grp][t] = facc;
    __syncthreads();
    if (grp == 0) {
      float h2 = fmaxf(part[0][t] + part[1][t] + b1[t], 0.f);
      h1s[t] = h2 * Wl[t];
    }
    __syncthreads();
    if (grp == 0) {
      for (int s = 64; s > 0; s >>= 1) {
        if (t < s) h1s[t] += h1s[t + s];
        __syncthreads();
      }
      if (t == 0) out[0] = 1.f / (1.f + expf(-(h1s[0] + bl[0])));
    }
  }
}

extern "C" void kernel_launch(void* const* d_in, const int* in_sizes, int n_in,
                              void* d_out, int out_size, void* d_ws, size_t ws_size,
                              hipStream_t stream) {
  const float* x  = (const float*)d_in[0];
  const int* g    = (const int*)d_in[1];
  const int* lg   = (const int*)d_in[2];
  const int* pidx = (const int*)d_in[3];
  const float* W0 = (const float*)d_in[4];
  const float* b0 = (const float*)d_in[5];
  const float* W1 = (const float*)d_in[6];
  const float* b1 = (const float*)d_in[7];
  const float* Wl = (const float*)d_in[8];
  const float* bl = (const float*)d_in[9];
  float* out = (float*)d_out;

  int e_g = in_sizes[1] / 2;   // 200000
  int e_lg = in_sizes[2] / 2;  // 2000000

  // ---- workspace layout ----
  char* ws = (char*)d_ws;
  size_t off = 0;
  auto take = [&](size_t bytes) {
    size_t cur = off;
    off = (off + bytes + 15) & ~(size_t)15;
    return cur;
  };
  const size_t nbits_words = ((size_t)e_g + 31) / 32;
  int* cnt        = (int*)(ws + take(16 * 4));
  unsigned* bits2 = (unsigned*)(ws + take(nbits_words * 4));
  unsigned* bits3 = (unsigned*)(ws + take(nbits_words * 4));
  int* degc       = (int*)(ws + take((size_t)MAX_S3 * 4));
  size_t zero_bytes = off;  // ~70 KB (memset dispatch boundary flushes to mem)
  int* list1      = (int*)(ws + take(MAX_L1 * 4));
  int* s2_list    = (int*)(ws + take(MAX_S2 * 4));
  int* s2pos      = (int*)(ws + take((size_t)e_g * 4));
  int2* list2     = (int2*)(ws + take((size_t)MAX_L2 * 8));
  int* s3_list    = (int*)(ws + take((size_t)MAX_S3 * 4));
  int* slot       = (int*)(ws + take((size_t)e_g * 4));
  float* hw0      = (float*)(ws + take((size_t)MAX_S3 * 128 * 4));
  float* hw1      = (float*)(ws + take((size_t)MAX_S2 * 128 * 4));
  (void)ws_size;

  hipMemsetAsync(d_ws, 0, zero_bytes, stream);

  void* kargs[] = {
      (void*)&x,   (void*)&g,     (void*)&lg,    (void*)&pidx,
      (void*)&W0,  (void*)&b0,    (void*)&W1,    (void*)&b1,
      (void*)&Wl,  (void*)&bl,    (void*)&out,
      (void*)&cnt, (void*)&bits2, (void*)&bits3, (void*)&degc,
      (void*)&list1, (void*)&s2_list, (void*)&s2pos, (void*)&list2,
      (void*)&s3_list, (void*)&slot, (void*)&hw0, (void*)&hw1,
      (void*)&e_g, (void*)&e_lg};
  hipLaunchCooperativeKernel((const void*)fused_gnn, dim3(GRID_B), dim3(256),
                             kargs, 0, stream);
}

// Round 7
// 210.559 us; speedup vs baseline: 2.6134x; 2.6134x over previous
//
#include <hip/hip_runtime.h>
#include <math.h>

// EdgeConvGNN: 2-layer GCN on a line graph; output = sigmoid(h2[idx0].Wl+bl).
// Only the 2-hop neighborhood of idx0 is live (E[deg]=10 -> ~120 nodes).
//
// Measured history: stream-ordered stages cost ~15-20us each (R3/R5: 148-154us
// total); grid barriers WITH __threadfence cost ~110us EACH regardless of
// fence granularity (R2: 6 bars = 622us, R6: 4 bars = 450us) because each
// agent-scope fence = buffer_wbl2 = full per-XCD L2 tag-walk, serialized.
//
// This version: ONE cooperative kernel, FENCE-FREE barriers. All cross-phase
// shared writes are device-scope atomic RMWs (memory-side coherent, proven by
// R1's 62MB atomic write traffic + guide m20). __syncthreads drains vmcnt
// (RMWs wait for returns) before the arrival atomicAdd; spinners can only see
// ctr==GRID after all arrivals. L2s are invalidated at dispatch start and no
// shared slab is plain-written, so no stale lines can exist.
// Phases:  A scan col[] -> list1 (col==idx0), S2 = {idx0} U rows  (bit dedup)
//            || 8 warm blocks (one per XCD) pull W0,W1 into L2
//          B scan col[] -> list2 (col in S2), S3 = S2 U rows(list2)
//          C blocks<448: degc[slot[c]]++ for c in S3 (~1.2K atomics)
//            blocks>=448: hw0[b] = concat(x[src],x[dst]) @ W0 per S3 node
//          D block b<ns2: LDS-filter list2; h1=relu(agg+self+b0); hw1=h1@W1
//            ticket: last D block -> E final aggregate at idx0 + sigmoid

#define MAX_L1 512
#define MAX_S2 (MAX_L1 + 8)
#define MAX_L2 4096
#define MAX_S3 (MAX_L2 + MAX_S2 + 8)
#define GRID_B 512
#define SCAN_B 448
#define WARM_B 8
#define LDSE 2048
#define MAXM 256

enum { CNT_L1 = 0, CNT_S2 = 1, CNT_L2 = 2, CNT_S3 = 3,
       BAR_A = 32, BAR_B = 64, BAR_C = 96, CNT_TICKET = 160 };  // own lines

// publish: device-scope RMW -> memory-side coherence point, bypasses L1/L2,
// and (return value) retires vmcnt only when globally performed.
__device__ __forceinline__ void pubi(int* p, int v) { atomicExch(p, v); }
__device__ __forceinline__ void pubf(float* p, float v) { atomicExch(p, v); }
__device__ __forceinline__ void pub2(int2* p, int2 v) {
  unsigned long long u =
      (unsigned long long)(unsigned)v.x | ((unsigned long long)(unsigned)v.y << 32);
  atomicExch((unsigned long long*)p, u);
}

// fence-free grid barrier: __syncthreads (drains block's vmcnt) + one
// memory-side atomic arrival per block + relaxed agent spin.
__device__ __forceinline__ void gbar(int* ctr, int expected) {
  __syncthreads();
  if (threadIdx.x == 0) {
    atomicAdd(ctr, 1);
    while (__hip_atomic_load(ctr, __ATOMIC_RELAXED,
                             __HIP_MEMORY_SCOPE_AGENT) < expected)
      __builtin_amdgcn_s_sleep(8);
  }
  __syncthreads();
}

__device__ __forceinline__ void insert_s3(int n, unsigned* bits3, int* cnt,
                                          int* s3_list, int* slot) {
  unsigned m = 1u << (n & 31);
  if (!(atomicOr(&bits3[n >> 5], m) & m)) {
    int p = atomicAdd(&cnt[CNT_S3], 1);
    if (p < MAX_S3) { pubi(&s3_list[p], n); pubi(&slot[n], p); }
  }
}

__device__ __forceinline__ void insert_s2(int n, unsigned* bits2, int* cnt,
                                          int* s2_list, int* s2pos,
                                          unsigned* bits3, int* s3_list,
                                          int* slot) {
  unsigned m = 1u << (n & 31);
  if (!(atomicOr(&bits2[n >> 5], m) & m)) {
    int p = atomicAdd(&cnt[CNT_S2], 1);
    if (p < MAX_S2) { pubi(&s2_list[p], n); pubi(&s2pos[n], p); }
  }
  insert_s3(n, bits3, cnt, s3_list, slot);
}

__global__ void __launch_bounds__(256)
fused_gnn(const float* __restrict__ x, const int* __restrict__ g,
          const int* __restrict__ lg, const int* __restrict__ pidx,
          const float* __restrict__ W0, const float* __restrict__ b0,
          const float* __restrict__ W1, const float* __restrict__ b1,
          const float* __restrict__ Wl, const float* __restrict__ bl,
          float* __restrict__ out,
          int* __restrict__ cnt, unsigned* __restrict__ bits2,
          unsigned* __restrict__ bits3, int* __restrict__ degc,
          int* __restrict__ list1, int* __restrict__ s2_list,
          int* __restrict__ s2pos, int2* __restrict__ list2,
          int* __restrict__ s3_list, int* __restrict__ slot,
          float* __restrict__ hw0, float* __restrict__ hw1,
          int e_g, int e_lg) {
  const int tid = threadIdx.x;
  const int bid = blockIdx.x;
  const int idx0 = pidx[0];
  const int* __restrict__ col = lg + e_lg;
  const int n4 = ((((uintptr_t)col) & 15) == 0) ? (e_lg >> 2) : 0;
  const int4* __restrict__ col4 = (const int4*)col;

  __shared__ int2 eLDS[LDSE];
  __shared__ float part[2][128];
  __shared__ float h1s[128];
  __shared__ int mslot[MAXM];
  __shared__ float mnorm[MAXM];
  __shared__ int nmatch;
  __shared__ int is_last;

  // ---- phase A: list1 = edges with col==idx0; S2 = {idx0} U rows ----
  if (bid < SCAN_B) {
    const int gtid = bid * 256 + tid;
    const int gstride = SCAN_B * 256;
    if (gtid == 0)
      insert_s2(idx0, bits2, cnt, s2_list, s2pos, bits3, s3_list, slot);
    for (int i = gtid; i < n4; i += gstride) {
      int4 v = col4[i];
      int cc[4] = {v.x, v.y, v.z, v.w};
#pragma unroll
      for (int k = 0; k < 4; ++k) {
        if (cc[k] == idx0) {
          int r = lg[i * 4 + k];
          int p = atomicAdd(&cnt[CNT_L1], 1);
          if (p < MAX_L1) pubi(&list1[p], r);
          insert_s2(r, bits2, cnt, s2_list, s2pos, bits3, s3_list, slot);
        }
      }
    }
    for (int e = n4 * 4 + gtid; e < e_lg; e += gstride) {
      if (col[e] == idx0) {
        int r = lg[e];
        int p = atomicAdd(&cnt[CNT_L1], 1);
        if (p < MAX_L1) pubi(&list1[p], r);
        insert_s2(r, bits2, cnt, s2_list, s2pos, bits3, s3_list, slot);
      }
    }
  } else if (bid < SCAN_B + WARM_B) {
    // warm W0 + W1 (128 KB) into this XCD's L2 (blocks 448..455 -> XCD 0..7)
    float acc = 0.f;
    const float4* w0v = (const float4*)W0;
    const float4* w1v = (const float4*)W1;
    for (int i = tid; i < 4096; i += 256) {
      float4 a = w0v[i], b = w1v[i];
      acc += a.x + a.y + a.z + a.w + b.x + b.y + b.z + b.w;
    }
    asm volatile("" ::"v"(acc));  // keep the warm loads live
  }
  gbar(&cnt[BAR_A], GRID_B);

  // ---- phase B: list2 = edges with col in S2; S3 += rows(list2) ----
  if (bid < SCAN_B) {
    const int gtid = bid * 256 + tid;
    const int gstride = SCAN_B * 256;
    for (int i = gtid; i < n4; i += gstride) {
      int4 v = col4[i];
      int cc[4] = {v.x, v.y, v.z, v.w};
#pragma unroll
      for (int k = 0; k < 4; ++k) {
        int c = cc[k];
        if ((bits2[c >> 5] >> (c & 31)) & 1u) {
          int r = lg[i * 4 + k];
          int p = atomicAdd(&cnt[CNT_L2], 1);
          if (p < MAX_L2) pub2(&list2[p], make_int2(r, c));
          insert_s3(r, bits3, cnt, s3_list, slot);
        }
      }
    }
    for (int e = n4 * 4 + gtid; e < e_lg; e += gstride) {
      int c = col[e];
      if ((bits2[c >> 5] >> (c & 31)) & 1u) {
        int r = lg[e];
        int p = atomicAdd(&cnt[CNT_L2], 1);
        if (p < MAX_L2) pub2(&list2[p], make_int2(r, c));
        insert_s3(r, bits3, cnt, s3_list, slot);
      }
    }
  }
  gbar(&cnt[BAR_B], GRID_B);

  // ---- phase C: deg scan (blocks < SCAN_B) || hw0 matvecs (last 64) ----
  if (bid < SCAN_B) {
    const int gtid = bid * 256 + tid;
    const int gstride = SCAN_B * 256;
    for (int i = gtid; i < n4; i += gstride) {
      int4 v = col4[i];
      int cc[4] = {v.x, v.y, v.z, v.w};
#pragma unroll
      for (int k = 0; k < 4; ++k) {
        int c = cc[k];
        if ((bits3[c >> 5] >> (c & 31)) & 1u) atomicAdd(&degc[slot[c]], 1);
      }
    }
    for (int e = n4 * 4 + gtid; e < e_lg; e += gstride) {
      int c = col[e];
      if ((bits3[c >> 5] >> (c & 31)) & 1u) atomicAdd(&degc[slot[c]], 1);
    }
  } else {
    int ns3 = min(cnt[CNT_S3], MAX_S3);
    int hb = (bid - SCAN_B) * 2 + (tid >> 7);  // 128 half-block units
    int t = tid & 127;
    for (int b = hb; b < ns3; b += (GRID_B - SCAN_B) * 2) {
      int node = s3_list[b];
      int src = g[node];
      int dst = g[e_g + node];
      float acc = 0.f;
#pragma unroll 8
      for (int k = 0; k < 64; ++k) acc += x[src * 64 + k] * W0[k * 128 + t];
#pragma unroll 8
      for (int k = 0; k < 64; ++k) acc += x[dst * 64 + k] * W0[(64 + k) * 128 + t];
      pubf(&hw0[b * 128 + t], acc);
    }
  }
  gbar(&cnt[BAR_C], GRID_B);

  // ---- phase D: per S2 node, h1 = relu(agg+self+b0); hw1 = h1 @ W1 ----
  int ns2 = min(cnt[CNT_S2], MAX_S2);
  if (bid >= ns2) return;  // exited waves don't block remaining barriers
  {
    int n2 = min(cnt[CNT_L2], MAX_L2);
    int j = s2_list[bid];
    int slot_j = slot[j];
    if (tid == 0) nmatch = 0;
    int n2l = min(n2, LDSE);
    for (int i = tid; i < n2l; i += 256) eLDS[i] = list2[i];
    __syncthreads();
    // pre-filter matching edges into dense LDS lists
    for (int i = tid; i < n2; i += 256) {
      int2 e = (i < LDSE) ? eLDS[i] : list2[i];
      if (e.y == j) {
        int p = atomicAdd(&nmatch, 1);
        if (p < MAXM) {
          int s = slot[e.x];
          mslot[p] = s;
          mnorm[p] = rsqrtf((float)degc[s] + 1.0f);
        }
      }
    }
    __syncthreads();
    int nm = min(nmatch, MAXM);
    int t = tid & 127;
    int grp = tid >> 7;
    float dj = rsqrtf((float)degc[slot_j] + 1.0f);
    float acc = (grp == 0) ? hw0[slot_j * 128 + t] * dj * dj + b0[t] : 0.f;
    for (int m = grp; m < nm; m += 2)
      acc += hw0[mslot[m] * 128 + t] * (mnorm[m] * dj);
    part[grp][t] = acc;
    __syncthreads();
    if (grp == 0) h1s[t] = fmaxf(part[0][t] + part[1][t], 0.f);
    __syncthreads();
    float a2 = 0.f;
    int k0 = grp * 64;
#pragma unroll 8
    for (int k = 0; k < 64; ++k) a2 += h1s[k0 + k] * W1[(k0 + k) * 128 + t];
    part[grp][t] = a2;
    __syncthreads();
    if (grp == 0) pubf(&hw1[bid * 128 + t], part[0][t] + part[1][t]);
  }

  // ---- ticket: last finishing D block runs the final phase ----
  __syncthreads();  // drains hw1 publishes (vmcnt0) for the whole block
  if (tid == 0) is_last = (atomicAdd(&cnt[CNT_TICKET], 1) == ns2 - 1);
  __syncthreads();
  if (!is_last) return;

  // ---- phase E: final aggregate at idx0 + sigmoid ----
  {
    int t = tid & 127;
    int grp = tid >> 7;
    float d0 = rsqrtf((float)degc[slot[idx0]] + 1.0f);
    float facc = (grp == 0) ? hw1[s2pos[idx0] * 128 + t] * d0 * d0 : 0.f;
    int n1 = min(cnt[CNT_L1], MAX_L1);
    for (int i = grp; i < n1; i += 2) {
      int r = list1[i];
      float dr = rsqrtf((float)degc[slot[r]] + 1.0f);
      facc += hw1[s2pos[r] * 128 + t] * (dr * d0);
    }
    part[grp][t] = facc;
    __syncthreads();
    if (grp == 0) {
      float h2 = fmaxf(part[0][t] + part[1][t] + b1[t], 0.f);
      h1s[t] = h2 * Wl[t];
    }
    __syncthreads();
    if (grp == 0) {  // grp1 waves exit; HW barrier counts only resident waves
      for (int s = 64; s > 0; s >>= 1) {
        if (t < s) h1s[t] += h1s[t + s];
        __syncthreads();
      }
      if (t == 0) out[0] = 1.f / (1.f + expf(-(h1s[0] + bl[0])));
    }
  }
}

extern "C" void kernel_launch(void* const* d_in, const int* in_sizes, int n_in,
                              void* d_out, int out_size, void* d_ws, size_t ws_size,
                              hipStream_t stream) {
  const float* x  = (const float*)d_in[0];
  const int* g    = (const int*)d_in[1];
  const int* lg   = (const int*)d_in[2];
  const int* pidx = (const int*)d_in[3];
  const float* W0 = (const float*)d_in[4];
  const float* b0 = (const float*)d_in[5];
  const float* W1 = (const float*)d_in[6];
  const float* b1 = (const float*)d_in[7];
  const float* Wl = (const float*)d_in[8];
  const float* bl = (const float*)d_in[9];
  float* out = (float*)d_out;

  int e_g = in_sizes[1] / 2;   // 200000
  int e_lg = in_sizes[2] / 2;  // 2000000

  // ---- workspace layout ----
  char* ws = (char*)d_ws;
  size_t off = 0;
  auto take = [&](size_t bytes) {
    size_t cur = off;
    off = (off + bytes + 15) & ~(size_t)15;
    return cur;
  };
  const size_t nbits_words = ((size_t)e_g + 31) / 32;
  int* cnt        = (int*)(ws + take(192 * 4));   // counters + padded barriers
  unsigned* bits2 = (unsigned*)(ws + take(nbits_words * 4));
  unsigned* bits3 = (unsigned*)(ws + take(nbits_words * 4));
  int* degc       = (int*)(ws + take((size_t)MAX_S3 * 4));
  size_t zero_bytes = off;  // ~69 KB; memset dispatch boundary flushes zeros
  int* list1      = (int*)(ws + take(MAX_L1 * 4));
  int* s2_list    = (int*)(ws + take(MAX_S2 * 4));
  int* s2pos      = (int*)(ws + take((size_t)e_g * 4));
  int2* list2     = (int2*)(ws + take((size_t)MAX_L2 * 8));
  int* s3_list    = (int*)(ws + take((size_t)MAX_S3 * 4));
  int* slot       = (int*)(ws + take((size_t)e_g * 4));
  float* hw0      = (float*)(ws + take((size_t)MAX_S3 * 128 * 4));
  float* hw1      = (float*)(ws + take((size_t)MAX_S2 * 128 * 4));
  (void)ws_size;

  hipMemsetAsync(d_ws, 0, zero_bytes, stream);

  void* kargs[] = {
      (void*)&x,   (void*)&g,     (void*)&lg,    (void*)&pidx,
      (void*)&W0,  (void*)&b0,    (void*)&W1,    (void*)&b1,
      (void*)&Wl,  (void*)&bl,    (void*)&out,
      (void*)&cnt, (void*)&bits2, (void*)&bits3, (void*)&degc,
      (void*)&list1, (void*)&s2_list, (void*)&s2pos, (void*)&list2,
      (void*)&s3_list, (void*)&slot, (void*)&hw0, (void*)&hw1,
      (void*)&e_g, (void*)&e_lg};
  hipLaunchCooperativeKernel((const void*)fused_gnn, dim3(GRID_B), dim3(256),
                             kargs, 0, stream);
}

// Round 9
// 177.143 us; speedup vs baseline: 3.1064x; 1.1886x over previous
//
#include <hip/hip_runtime.h>
#include <math.h>

// EdgeConvGNN: 2-layer GCN on a line graph; output = sigmoid(h2[idx0].Wl+bl).
// Only the 2-hop neighborhood of idx0 is live (E[deg]=10 -> ~120 nodes).
//
// Measured history:
//  - stream-ordered stages: ~15-20us each (R3/R5: 148-154us total)
//  - grid barrier WITH __threadfence: ~86-110us EACH (R2: 6 bars=622us,
//    R6: 4 bars=450us) -- agent fence = buffer_wbl2 = full L2 tag-walk.
//  - fence-free barrier (R7): ~0 per barrier; kernel = 102us ~= the
//    barrier-count regression intercept -> ~80-100us is hipLaunchCooperative
//    fixed overhead, not kernel body.
// This round: IDENTICAL kernel, REGULAR launch. Co-residency by construction:
// grid = 512 = 2 blocks/CU x 256 CUs, __launch_bounds__(256,2), 24 VGPR,
// 20.5KB LDS -> all blocks resident, spin barrier cannot deadlock.
//
// Cross-XCD visibility rules (audited): all cross-phase shared writes are
// device-scope atomic RMWs (memory-side coherent); every plain READ of a
// shared slab first touches it only after the producing phase's barrier, so
// no XCD can hold a stale L2 line for it. __syncthreads drains vmcnt (RMWs
// wait for returns) before tid0's arrival-add.
// Phases:  A scan col[] -> list1 (col==idx0), S2 = {idx0} U rows  (bit dedup)
//            || 8 warm blocks pull W0,W1 into their XCD L2
//          B scan col[] -> list2 (col in S2), S3 = S2 U rows(list2)
//          C blocks<448: degc[slot[c]]++ for c in S3 (~1.2K atomics)
//            blocks>=448: hw0[b] = concat(x[src],x[dst]) @ W0 per S3 node
//          D block b<ns2: LDS-filter list2; h1=relu(agg+self+b0); hw1=h1@W1
//            ticket: last D block -> E final aggregate at idx0 + sigmoid

#define MAX_L1 512
#define MAX_S2 (MAX_L1 + 8)
#define MAX_L2 4096
#define MAX_S3 (MAX_L2 + MAX_S2 + 8)
#define GRID_B 512
#define SCAN_B 448
#define WARM_B 8
#define LDSE 2048
#define MAXM 256

enum { CNT_L1 = 0, CNT_S2 = 1, CNT_L2 = 2, CNT_S3 = 3,
       BAR_A = 32, BAR_B = 64, BAR_C = 96, CNT_TICKET = 160 };  // own lines

// publish: device-scope RMW -> memory-side coherence point, bypasses L1/L2,
// and (return value) retires vmcnt only when globally performed.
__device__ __forceinline__ void pubi(int* p, int v) { atomicExch(p, v); }
__device__ __forceinline__ void pubf(float* p, float v) { atomicExch(p, v); }
__device__ __forceinline__ void pub2(int2* p, int2 v) {
  unsigned long long u =
      (unsigned long long)(unsigned)v.x | ((unsigned long long)(unsigned)v.y << 32);
  atomicExch((unsigned long long*)p, u);
}

// fence-free grid barrier: __syncthreads (drains block's vmcnt) + one
// memory-side atomic arrival per block + relaxed agent spin.
__device__ __forceinline__ void gbar(int* ctr, int expected) {
  __syncthreads();
  if (threadIdx.x == 0) {
    atomicAdd(ctr, 1);
    while (__hip_atomic_load(ctr, __ATOMIC_RELAXED,
                             __HIP_MEMORY_SCOPE_AGENT) < expected)
      __builtin_amdgcn_s_sleep(2);
  }
  __syncthreads();
}

__device__ __forceinline__ void insert_s3(int n, unsigned* bits3, int* cnt,
                                          int* s3_list, int* slot) {
  unsigned m = 1u << (n & 31);
  if (!(atomicOr(&bits3[n >> 5], m) & m)) {
    int p = atomicAdd(&cnt[CNT_S3], 1);
    if (p < MAX_S3) { pubi(&s3_list[p], n); pubi(&slot[n], p); }
  }
}

__device__ __forceinline__ void insert_s2(int n, unsigned* bits2, int* cnt,
                                          int* s2_list, int* s2pos,
                                          unsigned* bits3, int* s3_list,
                                          int* slot) {
  unsigned m = 1u << (n & 31);
  if (!(atomicOr(&bits2[n >> 5], m) & m)) {
    int p = atomicAdd(&cnt[CNT_S2], 1);
    if (p < MAX_S2) { pubi(&s2_list[p], n); pubi(&s2pos[n], p); }
  }
  insert_s3(n, bits3, cnt, s3_list, slot);
}

__global__ void __launch_bounds__(256, 2)
fused_gnn(const float* __restrict__ x, const int* __restrict__ g,
          const int* __restrict__ lg, const int* __restrict__ pidx,
          const float* __restrict__ W0, const float* __restrict__ b0,
          const float* __restrict__ W1, const float* __restrict__ b1,
          const float* __restrict__ Wl, const float* __restrict__ bl,
          float* __restrict__ out,
          int* __restrict__ cnt, unsigned* __restrict__ bits2,
          unsigned* __restrict__ bits3, int* __restrict__ degc,
          int* __restrict__ list1, int* __restrict__ s2_list,
          int* __restrict__ s2pos, int2* __restrict__ list2,
          int* __restrict__ s3_list, int* __restrict__ slot,
          float* __restrict__ hw0, float* __restrict__ hw1,
          int e_g, int e_lg) {
  const int tid = threadIdx.x;
  const int bid = blockIdx.x;
  const int idx0 = pidx[0];
  const int* __restrict__ col = lg + e_lg;
  const int n4 = ((((uintptr_t)col) & 15) == 0) ? (e_lg >> 2) : 0;
  const int4* __restrict__ col4 = (const int4*)col;

  __shared__ int2 eLDS[LDSE];
  __shared__ float part[2][128];
  __shared__ float h1s[128];
  __shared__ int mslot[MAXM];
  __shared__ float mnorm[MAXM];
  __shared__ int nmatch;
  __shared__ int is_last;

  // ---- phase A: list1 = edges with col==idx0; S2 = {idx0} U rows ----
  if (bid < SCAN_B) {
    const int gtid = bid * 256 + tid;
    const int gstride = SCAN_B * 256;
    if (gtid == 0)
      insert_s2(idx0, bits2, cnt, s2_list, s2pos, bits3, s3_list, slot);
    for (int i = gtid; i < n4; i += gstride) {
      int4 v = col4[i];
      int cc[4] = {v.x, v.y, v.z, v.w};
#pragma unroll
      for (int k = 0; k < 4; ++k) {
        if (cc[k] == idx0) {
          int r = lg[i * 4 + k];
          int p = atomicAdd(&cnt[CNT_L1], 1);
          if (p < MAX_L1) pubi(&list1[p], r);
          insert_s2(r, bits2, cnt, s2_list, s2pos, bits3, s3_list, slot);
        }
      }
    }
    for (int e = n4 * 4 + gtid; e < e_lg; e += gstride) {
      if (col[e] == idx0) {
        int r = lg[e];
        int p = atomicAdd(&cnt[CNT_L1], 1);
        if (p < MAX_L1) pubi(&list1[p], r);
        insert_s2(r, bits2, cnt, s2_list, s2pos, bits3, s3_list, slot);
      }
    }
  } else if (bid < SCAN_B + WARM_B) {
    // warm W0 + W1 (128 KB) into this XCD's L2 (blocks 448..455 -> XCD 0..7)
    float acc = 0.f;
    const float4* w0v = (const float4*)W0;
    const float4* w1v = (const float4*)W1;
    for (int i = tid; i < 4096; i += 256) {
      float4 a = w0v[i], b = w1v[i];
      acc += a.x + a.y + a.z + a.w + b.x + b.y + b.z + b.w;
    }
    asm volatile("" ::"v"(acc));  // keep the warm loads live
  }
  gbar(&cnt[BAR_A], GRID_B);

  // ---- phase B: list2 = edges with col in S2; S3 += rows(list2) ----
  if (bid < SCAN_B) {
    const int gtid = bid * 256 + tid;
    const int gstride = SCAN_B * 256;
    for (int i = gtid; i < n4; i += gstride) {
      int4 v = col4[i];
      int cc[4] = {v.x, v.y, v.z, v.w};
#pragma unroll
      for (int k = 0; k < 4; ++k) {
        int c = cc[k];
        if ((bits2[c >> 5] >> (c & 31)) & 1u) {
          int r = lg[i * 4 + k];
          int p = atomicAdd(&cnt[CNT_L2], 1);
          if (p < MAX_L2) pub2(&list2[p], make_int2(r, c));
          insert_s3(r, bits3, cnt, s3_list, slot);
        }
      }
    }
    for (int e = n4 * 4 + gtid; e < e_lg; e += gstride) {
      int c = col[e];
      if ((bits2[c >> 5] >> (c & 31)) & 1u) {
        int r = lg[e];
        int p = atomicAdd(&cnt[CNT_L2], 1);
        if (p < MAX_L2) pub2(&list2[p], make_int2(r, c));
        insert_s3(r, bits3, cnt, s3_list, slot);
      }
    }
  }
  gbar(&cnt[BAR_B], GRID_B);

  // ---- phase C: deg scan (blocks < SCAN_B) || hw0 matvecs (last 64) ----
  if (bid < SCAN_B) {
    const int gtid = bid * 256 + tid;
    const int gstride = SCAN_B * 256;
    for (int i = gtid; i < n4; i += gstride) {
      int4 v = col4[i];
      int cc[4] = {v.x, v.y, v.z, v.w};
#pragma unroll
      for (int k = 0; k < 4; ++k) {
        int c = cc[k];
        if ((bits3[c >> 5] >> (c & 31)) & 1u) atomicAdd(&degc[slot[c]], 1);
      }
    }
    for (int e = n4 * 4 + gtid; e < e_lg; e += gstride) {
      int c = col[e];
      if ((bits3[c >> 5] >> (c & 31)) & 1u) atomicAdd(&degc[slot[c]], 1);
    }
  } else {
    int ns3 = min(cnt[CNT_S3], MAX_S3);
    int hb = (bid - SCAN_B) * 2 + (tid >> 7);  // 128 half-block units
    int t = tid & 127;
    for (int b = hb; b < ns3; b += (GRID_B - SCAN_B) * 2) {
      int node = s3_list[b];
      int src = g[node];
      int dst = g[e_g + node];
      float acc = 0.f;
#pragma unroll 8
      for (int k = 0; k < 64; ++k) acc += x[src * 64 + k] * W0[k * 128 + t];
#pragma unroll 8
      for (int k = 0; k < 64; ++k) acc += x[dst * 64 + k] * W0[(64 + k) * 128 + t];
      pubf(&hw0[b * 128 + t], acc);
    }
  }
  gbar(&cnt[BAR_C], GRID_B);

  // ---- phase D: per S2 node, h1 = relu(agg+self+b0); hw1 = h1 @ W1 ----
  int ns2 = min(cnt[CNT_S2], MAX_S2);
  if (bid >= ns2) return;  // exited waves don't block remaining barriers
  {
    int n2 = min(cnt[CNT_L2], MAX_L2);
    int j = s2_list[bid];
    int slot_j = slot[j];
    if (tid == 0) nmatch = 0;
    int n2l = min(n2, LDSE);
    for (int i = tid; i < n2l; i += 256) eLDS[i] = list2[i];
    __syncthreads();
    // pre-filter matching edges into dense LDS lists
    for (int i = tid; i < n2; i += 256) {
      int2 e = (i < LDSE) ? eLDS[i] : list2[i];
      if (e.y == j) {
        int p = atomicAdd(&nmatch, 1);
        if (p < MAXM) {
          int s = slot[e.x];
          mslot[p] = s;
          mnorm[p] = rsqrtf((float)degc[s] + 1.0f);
        }
      }
    }
    __syncthreads();
    int nm = min(nmatch, MAXM);
    int t = tid & 127;
    int grp = tid >> 7;
    float dj = rsqrtf((float)degc[slot_j] + 1.0f);
    float acc = (grp == 0) ? hw0[slot_j * 128 + t] * dj * dj + b0[t] : 0.f;
    for (int m = grp; m < nm; m += 2)
      acc += hw0[mslot[m] * 128 + t] * (mnorm[m] * dj);
    part[grp][t] = acc;
    __syncthreads();
    if (grp == 0) h1s[t] = fmaxf(part[0][t] + part[1][t], 0.f);
    __syncthreads();
    float a2 = 0.f;
    int k0 = grp * 64;
#pragma unroll 8
    for (int k = 0; k < 64; ++k) a2 += h1s[k0 + k] * W1[(k0 + k) * 128 + t];
    part[grp][t] = a2;
    __syncthreads();
    if (grp == 0) pubf(&hw1[bid * 128 + t], part[0][t] + part[1][t]);
  }

  // ---- ticket: last finishing D block runs the final phase ----
  __syncthreads();  // drains hw1 publishes (vmcnt0) for the whole block
  if (tid == 0) is_last = (atomicAdd(&cnt[CNT_TICKET], 1) == ns2 - 1);
  __syncthreads();
  if (!is_last) return;

  // ---- phase E: final aggregate at idx0 + sigmoid ----
  {
    int t = tid & 127;
    int grp = tid >> 7;
    float d0 = rsqrtf((float)degc[slot[idx0]] + 1.0f);
    float facc = (grp == 0) ? hw1[s2pos[idx0] * 128 + t] * d0 * d0 : 0.f;
    int n1 = min(cnt[CNT_L1], MAX_L1);
    for (int i = grp; i < n1; i += 2) {
      int r = list1[i];
      float dr = rsqrtf((float)degc[slot[r]] + 1.0f);
      facc += hw1[s2pos[r] * 128 + t] * (dr * d0);
    }
    part[grp][t] = facc;
    __syncthreads();
    if (grp == 0) {
      float h2 = fmaxf(part[0][t] + part[1][t] + b1[t], 0.f);
      h1s[t] = h2 * Wl[t];
    }
    __syncthreads();
    if (grp == 0) {  // grp1 waves exit; HW barrier counts only resident waves
      for (int s = 64; s > 0; s >>= 1) {
        if (t < s) h1s[t] += h1s[t + s];
        __syncthreads();
      }
      if (t == 0) out[0] = 1.f / (1.f + expf(-(h1s[0] + bl[0])));
    }
  }
}

extern "C" void kernel_launch(void* const* d_in, const int* in_sizes, int n_in,
                              void* d_out, int out_size, void* d_ws, size_t ws_size,
                              hipStream_t stream) {
  const float* x  = (const float*)d_in[0];
  const int* g    = (const int*)d_in[1];
  const int* lg   = (const int*)d_in[2];
  const int* pidx = (const int*)d_in[3];
  const float* W0 = (const float*)d_in[4];
  const float* b0 = (const float*)d_in[5];
  const float* W1 = (const float*)d_in[6];
  const float* b1 = (const float*)d_in[7];
  const float* Wl = (const float*)d_in[8];
  const float* bl = (const float*)d_in[9];
  float* out = (float*)d_out;

  int e_g = in_sizes[1] / 2;   // 200000
  int e_lg = in_sizes[2] / 2;  // 2000000

  // ---- workspace layout ----
  char* ws = (char*)d_ws;
  size_t off = 0;
  auto take = [&](size_t bytes) {
    size_t cur = off;
    off = (off + bytes + 15) & ~(size_t)15;
    return cur;
  };
  const size_t nbits_words = ((size_t)e_g + 31) / 32;
  int* cnt        = (int*)(ws + take(192 * 4));   // counters + padded barriers
  unsigned* bits2 = (unsigned*)(ws + take(nbits_words * 4));
  unsigned* bits3 = (unsigned*)(ws + take(nbits_words * 4));
  int* degc       = (int*)(ws + take((size_t)MAX_S3 * 4));
  size_t zero_bytes = off;  // ~69 KB; memset dispatch boundary flushes zeros
  int* list1      = (int*)(ws + take(MAX_L1 * 4));
  int* s2_list    = (int*)(ws + take(MAX_S2 * 4));
  int* s2pos      = (int*)(ws + take((size_t)e_g * 4));
  int2* list2     = (int2*)(ws + take((size_t)MAX_L2 * 8));
  int* s3_list    = (int*)(ws + take((size_t)MAX_S3 * 4));
  int* slot       = (int*)(ws + take((size_t)e_g * 4));
  float* hw0      = (float*)(ws + take((size_t)MAX_S3 * 128 * 4));
  float* hw1      = (float*)(ws + take((size_t)MAX_S2 * 128 * 4));
  (void)ws_size;

  hipMemsetAsync(d_ws, 0, zero_bytes, stream);

  // REGULAR launch (A/B vs R7's cooperative): co-residency by construction,
  // grid = 2 blocks/CU x 256 CUs with __launch_bounds__(256,2).
  fused_gnn<<<dim3(GRID_B), dim3(256), 0, stream>>>(
      x, g, lg, pidx, W0, b0, W1, b1, Wl, bl, out,
      cnt, bits2, bits3, degc, list1, s2_list, s2pos, list2,
      s3_list, slot, hw0, hw1, e_g, e_lg);
}